// Round 7
// baseline (982.491 us; speedup 1.0000x reference)
//
#include <hip/hip_runtime.h>
#include <hip/hip_bf16.h>
#include <cmath>

typedef __hip_bfloat16 bf16;
typedef __attribute__((ext_vector_type(8))) __bf16 bf16x8;
typedef __attribute__((ext_vector_type(4))) float f32x4;
typedef __attribute__((ext_vector_type(4))) short short4v;

#define NROWS 50176   // 1024 windows * 49 tokens

static __device__ __forceinline__ float b2f(bf16 v) { return __bfloat162float(v); }
static __device__ __forceinline__ bf16 f2b(float v) { return __float2bfloat16(v); }

// async global->LDS 16B copy (dest must be linear: wave base + lane*16)
static __device__ __forceinline__ void gl16(const bf16* g, bf16* l) {
  __builtin_amdgcn_global_load_lds((const __attribute__((address_space(1))) void*)g,
                                   (__attribute__((address_space(3))) void*)l, 16, 0, 0);
}

// fast GELU: 0.5*v*(1+erf(v/sqrt2)), erf via A&S 7.1.26 (|eps|<=1.5e-7)
static __device__ __forceinline__ float fast_gelu(float v) {
  float z = v * 0.70710678118654752f;
  float a = fabsf(z);
  float t = __builtin_amdgcn_rcpf(fmaf(0.3275911f, a, 1.0f));
  float poly = t * fmaf(t, fmaf(t, fmaf(t, fmaf(t, 1.061405429f, -1.453152027f),
                                        1.421413741f), -0.284496736f), 0.254829592f);
  float e = exp2f(-a * a * 1.4426950408889634f);
  float erfz = copysignf(1.0f - poly * e, z);
  return 0.5f * v * (1.0f + erfz);
}

// map global window-row -> element base of pixel in x[16,56,56,512] after roll(-3,-3)
static __device__ __forceinline__ size_t pix_base(int row) {
  if (row >= NROWS) row = NROWS - 1;
  int win = row / 49, tok = row - win * 49;
  int b = win >> 6, wi = win & 63;
  int th = tok / 7, tw = tok - th * 7;
  int h = (wi >> 3) * 7 + th + 3; if (h >= 56) h -= 56;
  int w = (wi & 7) * 7 + tw + 3;  if (w >= 56) w -= 56;
  return (((size_t)b * 56 + h) * 56 + w) * 512;
}

// ---------------------------------------------------------------------------
__global__ __launch_bounds__(256) void diag_fill(float* out, float val, int n) {
  int i = blockIdx.x * 256 + threadIdx.x;
  if (i < n) out[i] = val;
}

// ---------------------------------------------------------------------------
// transpose f32 in[R][C] -> bf16 out[C][R]
__global__ __launch_bounds__(256) void transpose_f2b(const float* __restrict__ in,
                                                     bf16* __restrict__ out,
                                                     int R, int C) {
  __shared__ float tile[32][33];
  int c0 = blockIdx.x * 32, r0 = blockIdx.y * 32;
  int tx = threadIdx.x & 31, ty = threadIdx.x >> 5;
  for (int i = ty; i < 32; i += 8)
    tile[i][tx] = in[(size_t)(r0 + i) * C + c0 + tx];
  __syncthreads();
  for (int i = ty; i < 32; i += 8)
    out[(size_t)(c0 + i) * R + r0 + tx] = f2b(tile[tx][i]);
}

// f32 -> bf16 bulk convert (vectorized 8/thread)
__global__ __launch_bounds__(256) void conv_f2b(const float* __restrict__ in,
                                                bf16* __restrict__ outb, int n8) {
  for (int i = blockIdx.x * 256 + threadIdx.x; i < n8; i += gridDim.x * 256) {
    float4 u0 = *(const float4*)&in[(size_t)i * 8];
    float4 u1 = *(const float4*)&in[(size_t)i * 8 + 4];
    bf16 h8[8] = {f2b(u0.x), f2b(u0.y), f2b(u0.z), f2b(u0.w),
                  f2b(u1.x), f2b(u1.y), f2b(u1.z), f2b(u1.w)};
    *(uint4*)&outb[(size_t)i * 8] = *(uint4*)h8;
  }
}

// ---------------------------------------------------------------------------
__global__ void prep_small(const float* qb, const float* vb, const float* pb,
                           const float* f1b, const float* f2b_, const float* ls,
                           float* qkvb, float* pbf, float* f1bf, float* f2bf,
                           float* scale) {
  int tid = blockIdx.x * 256 + threadIdx.x;   // 0..2047
  if (tid < 512)       qkvb[tid] = qb[tid];
  else if (tid < 1024) qkvb[tid] = 0.f;
  else if (tid < 1536) qkvb[tid] = vb[tid - 1024];
  if (tid < 512)  pbf[tid]  = pb[tid];
  if (tid < 2048) f1bf[tid] = f1b[tid];
  if (tid < 512)  f2bf[tid] = f2b_[tid];
  if (tid < 16)   scale[tid] = expf(fminf(ls[tid], 4.6051701859880914f));
}

__global__ __launch_bounds__(256) void prep_cpb(const float* __restrict__ coords,
                                                const float* __restrict__ w1,
                                                const float* __restrict__ b1,
                                                const float* __restrict__ w2,
                                                float* __restrict__ table) {
  __shared__ float hid[512];
  __shared__ float part[256];
  int idx = blockIdx.x;   // 0..168
  float c0 = coords[idx * 2], c1 = coords[idx * 2 + 1];
  int tid = threadIdx.x;
  for (int h = tid; h < 512; h += 256) {
    float v = c0 * w1[h] + c1 * w1[512 + h] + b1[h];
    hid[h] = fmaxf(v, 0.f);
  }
  __syncthreads();
  int head = tid & 15, seg = tid >> 4;
  float s = 0.f;
  for (int h = seg * 32; h < seg * 32 + 32; ++h) s += hid[h] * w2[h * 16 + head];
  part[tid] = s;
  __syncthreads();
  if (tid < 16) {
    float t = 0.f;
    for (int sg = 0; sg < 16; ++sg) t += part[sg * 16 + tid];
    table[idx * 16 + tid] = t;
  }
}

__global__ void prep_bias(const float* __restrict__ table, const int* __restrict__ rpi,
                          float* __restrict__ bias_full) {
  int idx = blockIdx.x * 256 + threadIdx.x;
  if (idx >= 16 * 2401) return;
  int head = idx / 2401, ij = idx - head * 2401;
  float t = table[rpi[ij] * 16 + head];
  bias_full[idx] = 16.f / (1.f + expf(-t));
}

// combined bias+mask table: bm[w64][head][2401]
__global__ void prep_bm(const float* __restrict__ biasF, const float* __restrict__ amask,
                        float* __restrict__ bm) {
  int idx = blockIdx.x * 256 + threadIdx.x;
  if (idx >= 64 * 16 * 2401) return;
  int w = idx / (16 * 2401);
  int rem = idx - w * (16 * 2401);
  int h = rem / 2401, ij = rem - h * 2401;
  bm[idx] = biasF[h * 2401 + ij] + amask[w * 2401 + ij];
}

// ---------------------------------------------------------------------------
// bf16 MFMA GEMM, 128x64 tile, 4 waves of 64x32 (acc 32 regs -> 6 waves/SIMD).
// global_load_lds staging, linear LDS + XOR slot-swizzle on SOURCE address,
// inverse on fragment read (verified conflict-free, R5: SQ_LDS_BANK_CONFLICT=0).
// EPI: 1=bias, 2=bias+gelu(fast erf).  GATHER: A rows via pix_base.
// 1D grid, bijective XCD swizzle; consecutive bx share A row-panel per XCD L2.
template <int EPI, int GATHER>
__global__ __launch_bounds__(256, 6) void gemm_lds(const bf16* __restrict__ A, int lda,
                                                   const bf16* __restrict__ Bt,
                                                   bf16* __restrict__ C, int ldc,
                                                   const float* __restrict__ bias,
                                                   int K, int nbx, int row_off) {
  __shared__ __align__(16) bf16 As[128 * 32];   // 8 KB
  __shared__ __align__(16) bf16 Bs[64 * 32];    // 4 KB
  const int nwg = gridDim.x, bid = blockIdx.x;
  const int q = nwg >> 3, r = nwg & 7;
  const int xcd = bid & 7, coff = bid >> 3;
  const int wg = (xcd < r ? xcd * (q + 1) : r * (q + 1) + (xcd - r) * q) + coff;
  const int bx = wg % nbx, by = wg / nbx;
  const int row0 = by * 128, col0 = bx * 64;

  const int tid = threadIdx.x;
  const int lane = tid & 63;
  const int quad = lane >> 4, l15 = lane & 15;
  const int wave = tid >> 6;
  const int wm = (wave >> 1) * 64, wn = (wave & 1) * 32;
  const int xq = quad ^ ((l15 >> 1) & 3);   // inverse of the staging swizzle

  // A staging: 2 chunks/thread (rows ar0, ar0+64); B staging: 1 chunk/thread.
  const int ar0 = tid >> 2, as0 = tid & 3;
  const int ar1 = ar0 + 64;
  const int ax0 = as0 ^ ((ar0 >> 1) & 3);
  const int ax1 = as0 ^ ((ar1 >> 1) & 3);
  size_t ab0, ab1;
  if (GATHER) {
    ab0 = pix_base(row_off + row0 + ar0);
    ab1 = pix_base(row_off + row0 + ar1);
  } else {
    ab0 = (size_t)(row0 + ar0) * lda;
    ab1 = (size_t)(row0 + ar1) * lda;
  }
  const bf16* ap0 = A + ab0 + ax0 * 8;
  const bf16* ap1 = A + ab1 + ax1 * 8;
  const int br = tid >> 2;                       // 0..63
  const int bx0 = as0 ^ ((br >> 1) & 3);
  const bf16* bp0 = Bt + (size_t)(col0 + br) * K + bx0 * 8;
  bf16* la0 = As + tid * 8;
  bf16* la1 = As + (tid + 256) * 8;
  bf16* lb0 = Bs + tid * 8;

  f32x4 acc[4][2] = {};

  for (int k0 = 0; k0 < K; k0 += 32) {
    gl16(ap0 + k0, la0);
    gl16(ap1 + k0, la1);
    gl16(bp0 + k0, lb0);
    __syncthreads();
    bf16x8 af[4], bfr[2];
#pragma unroll
    for (int t = 0; t < 4; ++t)
      af[t] = *(const bf16x8*)&As[(wm + t * 16 + l15) * 32 + xq * 8];
#pragma unroll
    for (int t = 0; t < 2; ++t)
      bfr[t] = *(const bf16x8*)&Bs[(wn + t * 16 + l15) * 32 + xq * 8];
#pragma unroll
    for (int mt = 0; mt < 4; ++mt)
#pragma unroll
      for (int nt = 0; nt < 2; ++nt)
        acc[mt][nt] = __builtin_amdgcn_mfma_f32_16x16x32_bf16(af[mt], bfr[nt], acc[mt][nt], 0, 0, 0);
    __syncthreads();
  }

#pragma unroll
  for (int nt = 0; nt < 2; ++nt) {
    int gcol = col0 + wn + nt * 16 + l15;
    float bv = bias[gcol];
#pragma unroll
    for (int mt = 0; mt < 4; ++mt) {
      int grow = row0 + wm + mt * 16 + quad * 4;
#pragma unroll
      for (int rr = 0; rr < 4; ++rr) {
        float v = acc[mt][nt][rr] + bv;
        if (EPI == 2) v = fast_gelu(v);
        C[(size_t)(grow + rr) * ldc + gcol] = f2b(v);
      }
    }
  }
}

// ---------------------------------------------------------------------------
// Transposed-score MFMA cosine attention (unchanged from measured R4 winner).
__global__ __launch_bounds__(256, 4) void attn_mfma(const bf16* __restrict__ qkv,
                                                    const float* __restrict__ scale,
                                                    const float* __restrict__ bm,
                                                    bf16* __restrict__ outp, int win_off) {
  __shared__ __align__(16) __bf16 Vl[4][1984];   // per-wave V [49][40 pad]
  const int tid = threadIdx.x;
  const int wave = tid >> 6, lane = tid & 63;
  const int quad = lane >> 4, l15 = lane & 15;
  const int winl = blockIdx.x >> 2, hg = blockIdx.x & 3;
  const int head = hg * 4 + wave;
  const int wing = win_off + winl;
  const size_t rowbase = (size_t)winl * 49;
  const __bf16* base = (const __bf16*)qkv + rowbase * 1536 + head * 32;
  __bf16* Vw = Vl[wave];
  const float* bmh = bm + ((size_t)(wing & 63) * 16 + head) * 2401;
  const float sc = scale[head];

  bf16x8 vtmp[4];
  int vj[4], vdc[4];
#pragma unroll
  for (int t = 0; t < 4; ++t) {
    int c = lane + 64 * t; if (c > 195) c = 195;
    vj[t] = c >> 2; vdc[t] = (c & 3) << 3;
    vtmp[t] = *(const bf16x8*)(base + (size_t)vj[t] * 1536 + 1024 + vdc[t]);
  }

  bf16x8 khi[4], klo[4];
#pragma unroll
  for (int jt = 0; jt < 4; ++jt) {
    int j = jt * 16 + l15; if (j > 48) j = 48;
    bf16x8 raw = *(const bf16x8*)(base + (size_t)j * 1536 + 512 + quad * 8);
    float f[8]; float ss = 1e-20f;
#pragma unroll
    for (int e = 0; e < 8; ++e) { f[e] = (float)raw[e]; ss += f[e] * f[e]; }
    ss += __shfl_xor(ss, 16, 64);
    ss += __shfl_xor(ss, 32, 64);
    float inv = rsqrtf(ss);
#pragma unroll
    for (int e = 0; e < 8; ++e) {
      float v = f[e] * inv;
      __bf16 h = (__bf16)v;
      khi[jt][e] = h;
      klo[jt][e] = (__bf16)(v - (float)h);
    }
  }

#pragma unroll
  for (int t = 0; t < 4; ++t)
    *(bf16x8*)&Vw[vj[t] * 40 + vdc[t]] = vtmp[t];

  short4v vb[4][2];
#pragma unroll
  for (int jt = 0; jt < 4; ++jt)
#pragma unroll
    for (int n2 = 0; n2 < 2; ++n2) {
      short4v v;
#pragma unroll
      for (int e = 0; e < 4; ++e) {
        int j = jt * 16 + quad * 4 + e; if (j > 48) j = 48;
        v[e] = *(const short*)&Vw[j * 40 + n2 * 16 + l15];
      }
      vb[jt][n2] = v;
    }

  for (int it = 0; it < 4; ++it) {
    int qi = it * 16 + l15; if (qi > 48) qi = 48;
    bf16x8 raw = *(const bf16x8*)(base + (size_t)qi * 1536 + quad * 8);
    float f[8]; float ss = 1e-20f;
#pragma unroll
    for (int e = 0; e < 8; ++e) { f[e] = (float)raw[e]; ss += f[e] * f[e]; }
    ss += __shfl_xor(ss, 16, 64);
    ss += __shfl_xor(ss, 32, 64);
    float qinv = rsqrtf(ss) * sc;
    bf16x8 qhi, qlo;
#pragma unroll
    for (int e = 0; e < 8; ++e) {
      float v = f[e] * qinv;
      __bf16 h = (__bf16)v;
      qhi[e] = h;
      qlo[e] = (__bf16)(v - (float)h);
    }
    f32x4 s4[4];
#pragma unroll
    for (int jt = 0; jt < 4; ++jt) {
      f32x4 a = {0.f, 0.f, 0.f, 0.f};
      a = __builtin_amdgcn_mfma_f32_16x16x32_bf16(khi[jt], qhi, a, 0, 0, 0);
      a = __builtin_amdgcn_mfma_f32_16x16x32_bf16(klo[jt], qhi, a, 0, 0, 0);
      a = __builtin_amdgcn_mfma_f32_16x16x32_bf16(khi[jt], qlo, a, 0, 0, 0);
      s4[jt] = a;
    }
    int iio = qi * 49;
    float sv[4][4];
    float mx = -1e30f;
#pragma unroll
    for (int jt = 0; jt < 4; ++jt)
#pragma unroll
      for (int rr = 0; rr < 4; ++rr) {
        int j = jt * 16 + quad * 4 + rr;
        float s = (j < 49) ? s4[jt][rr] + bmh[iio + j] : -1e30f;
        sv[jt][rr] = s;
        mx = fmaxf(mx, s);
      }
    mx = fmaxf(mx, __shfl_xor(mx, 16, 64));
    mx = fmaxf(mx, __shfl_xor(mx, 32, 64));
    float sum = 0.f;
#pragma unroll
    for (int jt = 0; jt < 4; ++jt)
#pragma unroll
      for (int rr = 0; rr < 4; ++rr) {
        float e = exp2f((sv[jt][rr] - mx) * 1.4426950408889634f);
        sv[jt][rr] = e;
        sum += e;
      }
    sum += __shfl_xor(sum, 16, 64);
    sum += __shfl_xor(sum, 32, 64);
    float pinv = 1.f / sum;
    short4v pa[4];
#pragma unroll
    for (int jt = 0; jt < 4; ++jt)
#pragma unroll
      for (int rr = 0; rr < 4; ++rr) {
        __bf16 h = (__bf16)(sv[jt][rr] * pinv);
        pa[jt][rr] = *(short*)&h;
      }
    f32x4 o[2] = {};
#pragma unroll
    for (int jt = 0; jt < 4; ++jt) {
#pragma unroll
      for (int n2 = 0; n2 < 2; ++n2)
        o[n2] = __builtin_amdgcn_mfma_f32_16x16x16bf16_1k(pa[jt], vb[jt][n2], o[n2], 0, 0, 0);
    }
#pragma unroll
    for (int n2 = 0; n2 < 2; ++n2)
#pragma unroll
      for (int rr = 0; rr < 4; ++rr) {
        int i = it * 16 + quad * 4 + rr;
        if (i < 49)
          outp[(rowbase + i) * 1536 + head * 32 + n2 * 16 + l15] = f2b(o[n2][rr]);
      }
  }
}

// ---------------------------------------------------------------------------
// per (win,tok) row: x1 = x + LN(proj), scattered to pixel row of f32 out
// + bf16 copy x1b (feeds fc1 via global_load_lds)
__global__ __launch_bounds__(256) void ln_shift_add(const bf16* projq,
                                                    const float* __restrict__ x,
                                                    const float* __restrict__ gamma,
                                                    const float* __restrict__ beta,
                                                    float* __restrict__ x1,
                                                    bf16* __restrict__ x1b,
                                                    int row_off) {
  __shared__ float red[10];
  int grow = row_off + blockIdx.x;
  int win = grow / 49, tok = grow - win * 49;
  int b = win >> 6, wi = win & 63;
  int hs = (wi >> 3) * 7 + tok / 7;
  int wsc = (wi & 7) * 7 + tok % 7;
  int h = hs + 3; if (h >= 56) h -= 56;
  int w = wsc + 3; if (w >= 56) w -= 56;
  size_t pix = ((size_t)b * 56 + h) * 56 + w;
  const bf16* src = projq + (size_t)blockIdx.x * 1536 + 512;
  int tid = threadIdx.x;
  float a0 = b2f(src[tid]);
  float a1 = b2f(src[tid + 256]);
  float s = a0 + a1, qq = a0 * a0 + a1 * a1;
#pragma unroll
  for (int off = 32; off > 0; off >>= 1) {
    s += __shfl_down(s, off, 64);
    qq += __shfl_down(qq, off, 64);
  }
  int lane = tid & 63, wv = tid >> 6;
  if (lane == 0) { red[wv] = s; red[4 + wv] = qq; }
  __syncthreads();
  if (tid == 0) {
    red[8] = red[0] + red[1] + red[2] + red[3];
    red[9] = red[4] + red[5] + red[6] + red[7];
  }
  __syncthreads();
  float mu = red[8] * (1.f / 512.f);
  float inv = rsqrtf(fmaxf(red[9] * (1.f / 512.f) - mu * mu, 0.f) + 1e-5f);
  size_t base = pix * 512;
  float v0 = x[base + tid]       + (a0 - mu) * inv * gamma[tid]       + beta[tid];
  float v1 = x[base + tid + 256] + (a1 - mu) * inv * gamma[tid + 256] + beta[tid + 256];
  x1[base + tid]        = v0;
  x1[base + tid + 256]  = v1;
  x1b[base + tid]       = f2b(v0);
  x1b[base + tid + 256] = f2b(v1);
}

// out = x1 + LN(hsrc); x1/out alias (per-thread same-element RMW), f32
__global__ __launch_bounds__(256) void ln_add(const bf16* __restrict__ hsrc,
                                              float* x1,
                                              const float* __restrict__ gamma,
                                              const float* __restrict__ beta) {
  __shared__ float red[10];
  size_t base = (size_t)blockIdx.x * 512;
  int tid = threadIdx.x;
  float a0 = b2f(hsrc[base + tid]);
  float a1 = b2f(hsrc[base + tid + 256]);
  float s = a0 + a1, qq = a0 * a0 + a1 * a1;
#pragma unroll
  for (int off = 32; off > 0; off >>= 1) {
    s += __shfl_down(s, off, 64);
    qq += __shfl_down(qq, off, 64);
  }
  int lane = tid & 63, wv = tid >> 6;
  if (lane == 0) { red[wv] = s; red[4 + wv] = qq; }
  __syncthreads();
  if (tid == 0) {
    red[8] = red[0] + red[1] + red[2] + red[3];
    red[9] = red[4] + red[5] + red[6] + red[7];
  }
  __syncthreads();
  float mu = red[8] * (1.f / 512.f);
  float inv = rsqrtf(fmaxf(red[9] * (1.f / 512.f) - mu * mu, 0.f) + 1e-5f);
  x1[base + tid]       += (a0 - mu) * inv * gamma[tid]       + beta[tid];
  x1[base + tid + 256] += (a1 - mu) * inv * gamma[tid + 256] + beta[tid + 256];
}

// ---------------------------------------------------------------------------
extern "C" void kernel_launch(void* const* d_in, const int* in_sizes, int n_in,
                              void* d_out, int out_size, void* d_ws, size_t ws_size,
                              hipStream_t stream) {
  const float* x       = (const float*)d_in[0];
  const float* qkv_w   = (const float*)d_in[1];
  const float* q_bias  = (const float*)d_in[2];
  const float* v_bias  = (const float*)d_in[3];
  const float* proj_w  = (const float*)d_in[4];
  const float* proj_b  = (const float*)d_in[5];
  const float* logit_s = (const float*)d_in[6];
  const float* cpb_w1  = (const float*)d_in[7];
  const float* cpb_b1  = (const float*)d_in[8];
  const float* cpb_w2  = (const float*)d_in[9];
  const float* rct     = (const float*)d_in[10];
  const float* gamma1  = (const float*)d_in[11];
  const float* beta1   = (const float*)d_in[12];
  const float* gamma2  = (const float*)d_in[13];
  const float* beta2   = (const float*)d_in[14];
  const float* fc1_w   = (const float*)d_in[15];
  const float* fc1_b   = (const float*)d_in[16];
  const float* fc2_w   = (const float*)d_in[17];
  const float* fc2_b   = (const float*)d_in[18];
  const int*   rpi     = (const int*)d_in[19];
  const float* amask   = (const float*)d_in[20];
  float* out = (float*)d_out;   // f32 output per reference dtype

  char* ws = (char*)d_ws;
  size_t cur = 0;
  auto alloc = [&](size_t bytes) { size_t o = cur; cur += (bytes + 255) & ~(size_t)255; return o; };
  size_t o_qkvb = alloc(1536 * 4);
  size_t o_pb   = alloc(512 * 4);
  size_t o_f1b  = alloc(2048 * 4);
  size_t o_f2b  = alloc(512 * 4);
  size_t o_scal = alloc(16 * 4);
  size_t o_tab  = alloc(169 * 16 * 4);
  size_t o_bias = alloc(16 * 2401 * 4);
  size_t o_bm   = alloc((size_t)64 * 16 * 2401 * 4);
  size_t o_wt1  = alloc((size_t)1536 * 512 * 2);
  size_t o_wt2  = alloc((size_t)512 * 512 * 2);
  size_t o_wt3  = alloc((size_t)2048 * 512 * 2);
  size_t o_wt4  = alloc((size_t)512 * 2048 * 2);
  size_t o_xb   = alloc((size_t)NROWS * 512 * 2);
  size_t o_x1b  = alloc((size_t)NROWS * 512 * 2);
  size_t o_big  = cur;
  size_t avail  = (ws_size > o_big) ? ws_size - o_big : 0;

  // --- adaptive tier selection from actual ws_size ---
  const int wopts[] = {1024, 512, 256, 128, 64, 32, 16, 8};
  int wA = 0, padA = 0;
  for (int i = 0; i < 8; ++i) {
    int rows = wopts[i] * 49;
    int pad = (rows + 127) & ~127;
    if ((size_t)pad * 1536 * 2 <= avail) { wA = wopts[i]; padA = pad; break; }
  }
  const int ropts[] = {25088, 12544, 6272, 3584, 1792, 896, 512, 256};
  int rB = 0;
  for (int i = 0; i < 8; ++i)
    if ((size_t)ropts[i] * 2560 * 2 <= avail) { rB = ropts[i]; break; }

  if (!wA || !rB) {
    float v = 20000.f + (float)(ws_size >> 20);
    diag_fill<<<(out_size + 255) / 256, 256, 0, stream>>>(out, v, out_size);
    return;
  }

  float* qkvb  = (float*)(ws + o_qkvb);
  float* pbf   = (float*)(ws + o_pb);
  float* f1bf  = (float*)(ws + o_f1b);
  float* f2bf  = (float*)(ws + o_f2b);
  float* scal  = (float*)(ws + o_scal);
  float* tab   = (float*)(ws + o_tab);
  float* biasF = (float*)(ws + o_bias);
  float* bmF   = (float*)(ws + o_bm);
  bf16* wt1 = (bf16*)(ws + o_wt1);
  bf16* wt2 = (bf16*)(ws + o_wt2);
  bf16* wt3 = (bf16*)(ws + o_wt3);
  bf16* wt4 = (bf16*)(ws + o_wt4);
  bf16* xb  = (bf16*)(ws + o_xb);
  bf16* x1b = (bf16*)(ws + o_x1b);
  bf16* big = (bf16*)(ws + o_big);

  transpose_f2b<<<dim3(48, 16), 256, 0, stream>>>(qkv_w, wt1, 512, 1536);
  transpose_f2b<<<dim3(16, 16), 256, 0, stream>>>(proj_w, wt2, 512, 512);
  transpose_f2b<<<dim3(64, 16), 256, 0, stream>>>(fc1_w, wt3, 512, 2048);
  transpose_f2b<<<dim3(16, 64), 256, 0, stream>>>(fc2_w, wt4, 2048, 512);
  conv_f2b<<<2048, 256, 0, stream>>>(x, xb, NROWS * 512 / 8);

  prep_small<<<8, 256, 0, stream>>>(q_bias, v_bias, proj_b, fc1_b, fc2_b, logit_s,
                                    qkvb, pbf, f1bf, f2bf, scal);
  prep_cpb<<<169, 256, 0, stream>>>(rct, cpb_w1, cpb_b1, cpb_w2, tab);
  prep_bias<<<151, 256, 0, stream>>>(tab, rpi, biasF);
  prep_bm<<<(64 * 16 * 2401 + 255) / 256, 256, 0, stream>>>(biasF, amask, bmF);

  // Phase A: qkv -> attn -> proj -> x1 = x + LN(proj) scattered into f32 out
  for (int woff = 0; woff < 1024; woff += wA) {
    int row_off = woff * 49;
    int rows = wA * 49;
    int nby = padA / 128;
    bf16* qkvC = big;   // [padA,1536]
    gemm_lds<1, 1><<<24 * nby, 256, 0, stream>>>(xb, 0, wt1, qkvC, 1536, qkvb, 512, 24, row_off);
    attn_mfma<<<wA * 4, 256, 0, stream>>>(qkvC, scal, bmF, qkvC, woff);
    gemm_lds<1, 0><<<8 * nby, 256, 0, stream>>>(qkvC, 1536, wt2, qkvC + 512, 1536, pbf, 512, 8, 0);
    ln_shift_add<<<rows, 256, 0, stream>>>(qkvC, x, gamma1, beta1, out, x1b, row_off);
  }
  // Phase B: fc1 -> fc2 -> out += LN(h2)  (in-place on f32 out rows)
  for (int r0 = 0; r0 < NROWS; r0 += rB) {
    float* x1h = out + (size_t)r0 * 512;
    bf16* hC  = big;                        // [rB,2048]
    bf16* f2C = big + (size_t)rB * 2048;    // [rB,512]
    int nby = rB / 128;
    gemm_lds<2, 0><<<32 * nby, 256, 0, stream>>>(x1b + (size_t)r0 * 512, 512, wt3, hC, 2048, f1bf, 512, 32, 0);
    gemm_lds<1, 0><<<8 * nby, 256, 0, stream>>>(hC, 2048, wt4, f2C, 512, f2bf, 2048, 8, 0);
    ln_add<<<rB, 256, 0, stream>>>(f2C, x1h, gamma2, beta2);
  }
}

// Round 8
// 958.181 us; speedup vs baseline: 1.0254x; 1.0254x over previous
//
#include <hip/hip_runtime.h>
#include <hip/hip_bf16.h>
#include <cmath>

typedef __hip_bfloat16 bf16;
typedef __attribute__((ext_vector_type(8))) __bf16 bf16x8;
typedef __attribute__((ext_vector_type(4))) float f32x4;
typedef __attribute__((ext_vector_type(4))) short short4v;

#define NROWS 50176   // 1024 windows * 49 tokens

static __device__ __forceinline__ float b2f(bf16 v) { return __bfloat162float(v); }
static __device__ __forceinline__ bf16 f2b(float v) { return __float2bfloat16(v); }

// async global->LDS 16B copy (dest must be linear: wave base + lane*16)
static __device__ __forceinline__ void gl16(const bf16* g, bf16* l) {
  __builtin_amdgcn_global_load_lds((const __attribute__((address_space(1))) void*)g,
                                   (__attribute__((address_space(3))) void*)l, 16, 0, 0);
}

// fast GELU: 0.5*v*(1+erf(v/sqrt2)), erf via A&S 7.1.26 (|eps|<=1.5e-7)
static __device__ __forceinline__ float fast_gelu(float v) {
  float z = v * 0.70710678118654752f;
  float a = fabsf(z);
  float t = __builtin_amdgcn_rcpf(fmaf(0.3275911f, a, 1.0f));
  float poly = t * fmaf(t, fmaf(t, fmaf(t, fmaf(t, 1.061405429f, -1.453152027f),
                                        1.421413741f), -0.284496736f), 0.254829592f);
  float e = exp2f(-a * a * 1.4426950408889634f);
  float erfz = copysignf(1.0f - poly * e, z);
  return 0.5f * v * (1.0f + erfz);
}

// map global window-row -> element base of pixel in x[16,56,56,512] after roll(-3,-3)
static __device__ __forceinline__ size_t pix_base(int row) {
  if (row >= NROWS) row = NROWS - 1;
  int win = row / 49, tok = row - win * 49;
  int b = win >> 6, wi = win & 63;
  int th = tok / 7, tw = tok - th * 7;
  int h = (wi >> 3) * 7 + th + 3; if (h >= 56) h -= 56;
  int w = (wi & 7) * 7 + tw + 3;  if (w >= 56) w -= 56;
  return (((size_t)b * 56 + h) * 56 + w) * 512;
}

// ---------------------------------------------------------------------------
__global__ __launch_bounds__(256) void diag_fill(float* out, float val, int n) {
  int i = blockIdx.x * 256 + threadIdx.x;
  if (i < n) out[i] = val;
}

// ---------------------------------------------------------------------------
// transpose f32 in[R][C] -> bf16 out[C][R]
__global__ __launch_bounds__(256) void transpose_f2b(const float* __restrict__ in,
                                                     bf16* __restrict__ out,
                                                     int R, int C) {
  __shared__ float tile[32][33];
  int c0 = blockIdx.x * 32, r0 = blockIdx.y * 32;
  int tx = threadIdx.x & 31, ty = threadIdx.x >> 5;
  for (int i = ty; i < 32; i += 8)
    tile[i][tx] = in[(size_t)(r0 + i) * C + c0 + tx];
  __syncthreads();
  for (int i = ty; i < 32; i += 8)
    out[(size_t)(c0 + i) * R + r0 + tx] = f2b(tile[tx][i]);
}

// f32 -> bf16 bulk convert (vectorized 8/thread)
__global__ __launch_bounds__(256) void conv_f2b(const float* __restrict__ in,
                                                bf16* __restrict__ outb, int n8) {
  for (int i = blockIdx.x * 256 + threadIdx.x; i < n8; i += gridDim.x * 256) {
    float4 u0 = *(const float4*)&in[(size_t)i * 8];
    float4 u1 = *(const float4*)&in[(size_t)i * 8 + 4];
    bf16 h8[8] = {f2b(u0.x), f2b(u0.y), f2b(u0.z), f2b(u0.w),
                  f2b(u1.x), f2b(u1.y), f2b(u1.z), f2b(u1.w)};
    *(uint4*)&outb[(size_t)i * 8] = *(uint4*)h8;
  }
}

// ---------------------------------------------------------------------------
__global__ void prep_small(const float* qb, const float* vb, const float* pb,
                           const float* f1b, const float* f2b_, const float* ls,
                           float* qkvb, float* pbf, float* f1bf, float* f2bf,
                           float* scale) {
  int tid = blockIdx.x * 256 + threadIdx.x;   // 0..2047
  if (tid < 512)       qkvb[tid] = qb[tid];
  else if (tid < 1024) qkvb[tid] = 0.f;
  else if (tid < 1536) qkvb[tid] = vb[tid - 1024];
  if (tid < 512)  pbf[tid]  = pb[tid];
  if (tid < 2048) f1bf[tid] = f1b[tid];
  if (tid < 512)  f2bf[tid] = f2b_[tid];
  if (tid < 16)   scale[tid] = expf(fminf(ls[tid], 4.6051701859880914f));
}

__global__ __launch_bounds__(256) void prep_cpb(const float* __restrict__ coords,
                                                const float* __restrict__ w1,
                                                const float* __restrict__ b1,
                                                const float* __restrict__ w2,
                                                float* __restrict__ table) {
  __shared__ float hid[512];
  __shared__ float part[256];
  int idx = blockIdx.x;   // 0..168
  float c0 = coords[idx * 2], c1 = coords[idx * 2 + 1];
  int tid = threadIdx.x;
  for (int h = tid; h < 512; h += 256) {
    float v = c0 * w1[h] + c1 * w1[512 + h] + b1[h];
    hid[h] = fmaxf(v, 0.f);
  }
  __syncthreads();
  int head = tid & 15, seg = tid >> 4;
  float s = 0.f;
  for (int h = seg * 32; h < seg * 32 + 32; ++h) s += hid[h] * w2[h * 16 + head];
  part[tid] = s;
  __syncthreads();
  if (tid < 16) {
    float t = 0.f;
    for (int sg = 0; sg < 16; ++sg) t += part[sg * 16 + tid];
    table[idx * 16 + tid] = t;
  }
}

__global__ void prep_bias(const float* __restrict__ table, const int* __restrict__ rpi,
                          float* __restrict__ bias_full) {
  int idx = blockIdx.x * 256 + threadIdx.x;
  if (idx >= 16 * 2401) return;
  int head = idx / 2401, ij = idx - head * 2401;
  float t = table[rpi[ij] * 16 + head];
  bias_full[idx] = 16.f / (1.f + expf(-t));
}

// combined bias+mask table: bm[w64][head][2401]
__global__ void prep_bm(const float* __restrict__ biasF, const float* __restrict__ amask,
                        float* __restrict__ bm) {
  int idx = blockIdx.x * 256 + threadIdx.x;
  if (idx >= 64 * 16 * 2401) return;
  int w = idx / (16 * 2401);
  int rem = idx - w * (16 * 2401);
  int h = rem / 2401, ij = rem - h * 2401;
  bm[idx] = biasF[h * 2401 + ij] + amask[w * 2401 + ij];
}

// ---------------------------------------------------------------------------
// bf16 MFMA GEMM, 128x64 tile, 4 waves of 64x32, ping-pong double-buffered
// LDS (ONE __syncthreads per K-step: stage t+1 issued BEFORE compute t, so
// the barrier's vmcnt drain overlaps ds_read+MFMA).  24 KB LDS -> 6 blocks/CU.
// Epilogue: tile bounced through padded LDS [128][72] -> 4x dwordx4 stores.
// EPI: 1=bias, 2=bias+gelu(fast erf).  GATHER: A rows via pix_base.
// 1D grid, bijective XCD swizzle; consecutive wg share A row-panel per XCD L2.
template <int EPI, int GATHER>
__global__ __launch_bounds__(256, 6) void gemm_lds(const bf16* __restrict__ A, int lda,
                                                   const bf16* __restrict__ Bt,
                                                   bf16* __restrict__ C, int ldc,
                                                   const float* __restrict__ bias,
                                                   int K, int nbx, int row_off) {
  __shared__ __align__(16) char smem[24576];
  bf16* As0 = (bf16*)smem;                 // 8 KB
  bf16* As1 = (bf16*)(smem + 8192);        // 8 KB
  bf16* Bs0 = (bf16*)(smem + 16384);       // 4 KB
  bf16* Bs1 = (bf16*)(smem + 20480);       // 4 KB
  bf16* Ct  = (bf16*)smem;                 // epilogue overlay [128][72] = 18 KB

  const int nwg = gridDim.x, bid = blockIdx.x;
  const int q = nwg >> 3, r = nwg & 7;
  const int xcd = bid & 7, coff = bid >> 3;
  const int wg = (xcd < r ? xcd * (q + 1) : r * (q + 1) + (xcd - r) * q) + coff;
  const int bx = wg % nbx, by = wg / nbx;
  const int row0 = by * 128, col0 = bx * 64;

  const int tid = threadIdx.x;
  const int lane = tid & 63;
  const int quad = lane >> 4, l15 = lane & 15;
  const int wave = tid >> 6;
  const int wm = (wave >> 1) * 64, wn = (wave & 1) * 32;
  const int xq = quad ^ ((l15 >> 1) & 3);   // inverse of the staging swizzle

  // staging addresses: A 2 chunks/thread (rows ar0, ar0+64), B 1 chunk/thread;
  // source column-slot XOR-swizzled so linear LDS reads back conflict-free.
  const int ar0 = tid >> 2, as0 = tid & 3;
  const int ar1 = ar0 + 64;
  const int ax0 = as0 ^ ((ar0 >> 1) & 3);
  const int ax1 = as0 ^ ((ar1 >> 1) & 3);
  size_t ab0, ab1;
  if (GATHER) {
    ab0 = pix_base(row_off + row0 + ar0);
    ab1 = pix_base(row_off + row0 + ar1);
  } else {
    ab0 = (size_t)(row0 + ar0) * lda;
    ab1 = (size_t)(row0 + ar1) * lda;
  }
  const bf16* ap0 = A + ab0 + ax0 * 8;
  const bf16* ap1 = A + ab1 + ax1 * 8;
  const int br = tid >> 2;
  const int bx0 = as0 ^ ((br >> 1) & 3);
  const bf16* bp0 = Bt + (size_t)(col0 + br) * K + bx0 * 8;

  f32x4 acc[4][2] = {};

#define STAGE(AS, BS, KK)                 \
  do {                                    \
    gl16(ap0 + (KK), (AS) + tid * 8);     \
    gl16(ap1 + (KK), (AS) + (tid + 256) * 8); \
    gl16(bp0 + (KK), (BS) + tid * 8);     \
  } while (0)

#define COMPUTE(AS, BS)                                                   \
  do {                                                                    \
    bf16x8 af[4], bfr[2];                                                 \
    _Pragma("unroll")                                                     \
    for (int t = 0; t < 4; ++t)                                           \
      af[t] = *(const bf16x8*)&(AS)[(wm + t * 16 + l15) * 32 + xq * 8];   \
    _Pragma("unroll")                                                     \
    for (int t = 0; t < 2; ++t)                                           \
      bfr[t] = *(const bf16x8*)&(BS)[(wn + t * 16 + l15) * 32 + xq * 8];  \
    _Pragma("unroll")                                                     \
    for (int mt = 0; mt < 4; ++mt)                                        \
      _Pragma("unroll")                                                   \
      for (int nt = 0; nt < 2; ++nt)                                      \
        acc[mt][nt] = __builtin_amdgcn_mfma_f32_16x16x32_bf16(af[mt], bfr[nt], acc[mt][nt], 0, 0, 0); \
  } while (0)

  STAGE(As0, Bs0, 0);
  __syncthreads();                       // drains stage of buf0
  for (int k0 = 0; k0 < K; k0 += 64) {   // K is a multiple of 64 (512/2048)
    if (k0 + 32 < K) STAGE(As1, Bs1, k0 + 32);
    COMPUTE(As0, Bs0);
    __syncthreads();                     // drains buf1 stage; WAR for buf0
    if (k0 + 64 < K) STAGE(As0, Bs0, k0 + 64);
    COMPUTE(As1, Bs1);
    __syncthreads();                     // drains buf0 stage; WAR for buf1 + epilogue overlay
  }
#undef STAGE
#undef COMPUTE

  // epilogue: acc -> padded LDS tile -> vectorized 16B stores
#pragma unroll
  for (int nt = 0; nt < 2; ++nt) {
    int lcol = wn + nt * 16 + l15;
    float bv = bias[col0 + lcol];
#pragma unroll
    for (int mt = 0; mt < 4; ++mt) {
      int lrow = wm + mt * 16 + quad * 4;
#pragma unroll
      for (int rr = 0; rr < 4; ++rr) {
        float v = acc[mt][nt][rr] + bv;
        if (EPI == 2) v = fast_gelu(v);
        Ct[(lrow + rr) * 72 + lcol] = f2b(v);
      }
    }
  }
  __syncthreads();
#pragma unroll
  for (int i = 0; i < 4; ++i) {
    int chunk = tid + i * 256;           // 0..1023 = 128 rows x 8 chunks
    int rw = chunk >> 3, c8 = chunk & 7;
    uint4 val = *(const uint4*)&Ct[rw * 72 + c8 * 8];
    *(uint4*)&C[(size_t)(row0 + rw) * ldc + col0 + c8 * 8] = val;
  }
}

// ---------------------------------------------------------------------------
// Transposed-score MFMA cosine attention (unchanged from measured R4 winner).
__global__ __launch_bounds__(256, 4) void attn_mfma(const bf16* __restrict__ qkv,
                                                    const float* __restrict__ scale,
                                                    const float* __restrict__ bm,
                                                    bf16* __restrict__ outp, int win_off) {
  __shared__ __align__(16) __bf16 Vl[4][1984];   // per-wave V [49][40 pad]
  const int tid = threadIdx.x;
  const int wave = tid >> 6, lane = tid & 63;
  const int quad = lane >> 4, l15 = lane & 15;
  const int winl = blockIdx.x >> 2, hg = blockIdx.x & 3;
  const int head = hg * 4 + wave;
  const int wing = win_off + winl;
  const size_t rowbase = (size_t)winl * 49;
  const __bf16* base = (const __bf16*)qkv + rowbase * 1536 + head * 32;
  __bf16* Vw = Vl[wave];
  const float* bmh = bm + ((size_t)(wing & 63) * 16 + head) * 2401;
  const float sc = scale[head];

  bf16x8 vtmp[4];
  int vj[4], vdc[4];
#pragma unroll
  for (int t = 0; t < 4; ++t) {
    int c = lane + 64 * t; if (c > 195) c = 195;
    vj[t] = c >> 2; vdc[t] = (c & 3) << 3;
    vtmp[t] = *(const bf16x8*)(base + (size_t)vj[t] * 1536 + 1024 + vdc[t]);
  }

  bf16x8 khi[4], klo[4];
#pragma unroll
  for (int jt = 0; jt < 4; ++jt) {
    int j = jt * 16 + l15; if (j > 48) j = 48;
    bf16x8 raw = *(const bf16x8*)(base + (size_t)j * 1536 + 512 + quad * 8);
    float f[8]; float ss = 1e-20f;
#pragma unroll
    for (int e = 0; e < 8; ++e) { f[e] = (float)raw[e]; ss += f[e] * f[e]; }
    ss += __shfl_xor(ss, 16, 64);
    ss += __shfl_xor(ss, 32, 64);
    float inv = rsqrtf(ss);
#pragma unroll
    for (int e = 0; e < 8; ++e) {
      float v = f[e] * inv;
      __bf16 h = (__bf16)v;
      khi[jt][e] = h;
      klo[jt][e] = (__bf16)(v - (float)h);
    }
  }

#pragma unroll
  for (int t = 0; t < 4; ++t)
    *(bf16x8*)&Vw[vj[t] * 40 + vdc[t]] = vtmp[t];

  short4v vb[4][2];
#pragma unroll
  for (int jt = 0; jt < 4; ++jt)
#pragma unroll
    for (int n2 = 0; n2 < 2; ++n2) {
      short4v v;
#pragma unroll
      for (int e = 0; e < 4; ++e) {
        int j = jt * 16 + quad * 4 + e; if (j > 48) j = 48;
        v[e] = *(const short*)&Vw[j * 40 + n2 * 16 + l15];
      }
      vb[jt][n2] = v;
    }

  for (int it = 0; it < 4; ++it) {
    int qi = it * 16 + l15; if (qi > 48) qi = 48;
    bf16x8 raw = *(const bf16x8*)(base + (size_t)qi * 1536 + quad * 8);
    float f[8]; float ss = 1e-20f;
#pragma unroll
    for (int e = 0; e < 8; ++e) { f[e] = (float)raw[e]; ss += f[e] * f[e]; }
    ss += __shfl_xor(ss, 16, 64);
    ss += __shfl_xor(ss, 32, 64);
    float qinv = rsqrtf(ss) * sc;
    bf16x8 qhi, qlo;
#pragma unroll
    for (int e = 0; e < 8; ++e) {
      float v = f[e] * qinv;
      __bf16 h = (__bf16)v;
      qhi[e] = h;
      qlo[e] = (__bf16)(v - (float)h);
    }
    f32x4 s4[4];
#pragma unroll
    for (int jt = 0; jt < 4; ++jt) {
      f32x4 a = {0.f, 0.f, 0.f, 0.f};
      a = __builtin_amdgcn_mfma_f32_16x16x32_bf16(khi[jt], qhi, a, 0, 0, 0);
      a = __builtin_amdgcn_mfma_f32_16x16x32_bf16(klo[jt], qhi, a, 0, 0, 0);
      a = __builtin_amdgcn_mfma_f32_16x16x32_bf16(khi[jt], qlo, a, 0, 0, 0);
      s4[jt] = a;
    }
    int iio = qi * 49;
    float sv[4][4];
    float mx = -1e30f;
#pragma unroll
    for (int jt = 0; jt < 4; ++jt)
#pragma unroll
      for (int rr = 0; rr < 4; ++rr) {
        int j = jt * 16 + quad * 4 + rr;
        float s = (j < 49) ? s4[jt][rr] + bmh[iio + j] : -1e30f;
        sv[jt][rr] = s;
        mx = fmaxf(mx, s);
      }
    mx = fmaxf(mx, __shfl_xor(mx, 16, 64));
    mx = fmaxf(mx, __shfl_xor(mx, 32, 64));
    float sum = 0.f;
#pragma unroll
    for (int jt = 0; jt < 4; ++jt)
#pragma unroll
      for (int rr = 0; rr < 4; ++rr) {
        float e = exp2f((sv[jt][rr] - mx) * 1.4426950408889634f);
        sv[jt][rr] = e;
        sum += e;
      }
    sum += __shfl_xor(sum, 16, 64);
    sum += __shfl_xor(sum, 32, 64);
    float pinv = 1.f / sum;
    short4v pa[4];
#pragma unroll
    for (int jt = 0; jt < 4; ++jt)
#pragma unroll
      for (int rr = 0; rr < 4; ++rr) {
        __bf16 h = (__bf16)(sv[jt][rr] * pinv);
        pa[jt][rr] = *(short*)&h;
      }
    f32x4 o[2] = {};
#pragma unroll
    for (int jt = 0; jt < 4; ++jt) {
#pragma unroll
      for (int n2 = 0; n2 < 2; ++n2)
        o[n2] = __builtin_amdgcn_mfma_f32_16x16x16bf16_1k(pa[jt], vb[jt][n2], o[n2], 0, 0, 0);
    }
#pragma unroll
    for (int n2 = 0; n2 < 2; ++n2)
#pragma unroll
      for (int rr = 0; rr < 4; ++rr) {
        int i = it * 16 + quad * 4 + rr;
        if (i < 49)
          outp[(rowbase + i) * 1536 + head * 32 + n2 * 16 + l15] = f2b(o[n2][rr]);
      }
  }
}

// ---------------------------------------------------------------------------
// per (win,tok) row: x1 = x + LN(proj), scattered to pixel row of f32 out
// + bf16 copy x1b (feeds fc1 via global_load_lds)
__global__ __launch_bounds__(256) void ln_shift_add(const bf16* projq,
                                                    const float* __restrict__ x,
                                                    const float* __restrict__ gamma,
                                                    const float* __restrict__ beta,
                                                    float* __restrict__ x1,
                                                    bf16* __restrict__ x1b,
                                                    int row_off) {
  __shared__ float red[10];
  int grow = row_off + blockIdx.x;
  int win = grow / 49, tok = grow - win * 49;
  int b = win >> 6, wi = win & 63;
  int hs = (wi >> 3) * 7 + tok / 7;
  int wsc = (wi & 7) * 7 + tok % 7;
  int h = hs + 3; if (h >= 56) h -= 56;
  int w = wsc + 3; if (w >= 56) w -= 56;
  size_t pix = ((size_t)b * 56 + h) * 56 + w;
  const bf16* src = projq + (size_t)blockIdx.x * 1536 + 512;
  int tid = threadIdx.x;
  float a0 = b2f(src[tid]);
  float a1 = b2f(src[tid + 256]);
  float s = a0 + a1, qq = a0 * a0 + a1 * a1;
#pragma unroll
  for (int off = 32; off > 0; off >>= 1) {
    s += __shfl_down(s, off, 64);
    qq += __shfl_down(qq, off, 64);
  }
  int lane = tid & 63, wv = tid >> 6;
  if (lane == 0) { red[wv] = s; red[4 + wv] = qq; }
  __syncthreads();
  if (tid == 0) {
    red[8] = red[0] + red[1] + red[2] + red[3];
    red[9] = red[4] + red[5] + red[6] + red[7];
  }
  __syncthreads();
  float mu = red[8] * (1.f / 512.f);
  float inv = rsqrtf(fmaxf(red[9] * (1.f / 512.f) - mu * mu, 0.f) + 1e-5f);
  size_t base = pix * 512;
  float v0 = x[base + tid]       + (a0 - mu) * inv * gamma[tid]       + beta[tid];
  float v1 = x[base + tid + 256] + (a1 - mu) * inv * gamma[tid + 256] + beta[tid + 256];
  x1[base + tid]        = v0;
  x1[base + tid + 256]  = v1;
  x1b[base + tid]       = f2b(v0);
  x1b[base + tid + 256] = f2b(v1);
}

// out = x1 + LN(hsrc); x1/out alias (per-thread same-element RMW), f32
__global__ __launch_bounds__(256) void ln_add(const bf16* __restrict__ hsrc,
                                              float* x1,
                                              const float* __restrict__ gamma,
                                              const float* __restrict__ beta) {
  __shared__ float red[10];
  size_t base = (size_t)blockIdx.x * 512;
  int tid = threadIdx.x;
  float a0 = b2f(hsrc[base + tid]);
  float a1 = b2f(hsrc[base + tid + 256]);
  float s = a0 + a1, qq = a0 * a0 + a1 * a1;
#pragma unroll
  for (int off = 32; off > 0; off >>= 1) {
    s += __shfl_down(s, off, 64);
    qq += __shfl_down(qq, off, 64);
  }
  int lane = tid & 63, wv = tid >> 6;
  if (lane == 0) { red[wv] = s; red[4 + wv] = qq; }
  __syncthreads();
  if (tid == 0) {
    red[8] = red[0] + red[1] + red[2] + red[3];
    red[9] = red[4] + red[5] + red[6] + red[7];
  }
  __syncthreads();
  float mu = red[8] * (1.f / 512.f);
  float inv = rsqrtf(fmaxf(red[9] * (1.f / 512.f) - mu * mu, 0.f) + 1e-5f);
  x1[base + tid]       += (a0 - mu) * inv * gamma[tid]       + beta[tid];
  x1[base + tid + 256] += (a1 - mu) * inv * gamma[tid + 256] + beta[tid + 256];
}

// ---------------------------------------------------------------------------
extern "C" void kernel_launch(void* const* d_in, const int* in_sizes, int n_in,
                              void* d_out, int out_size, void* d_ws, size_t ws_size,
                              hipStream_t stream) {
  const float* x       = (const float*)d_in[0];
  const float* qkv_w   = (const float*)d_in[1];
  const float* q_bias  = (const float*)d_in[2];
  const float* v_bias  = (const float*)d_in[3];
  const float* proj_w  = (const float*)d_in[4];
  const float* proj_b  = (const float*)d_in[5];
  const float* logit_s = (const float*)d_in[6];
  const float* cpb_w1  = (const float*)d_in[7];
  const float* cpb_b1  = (const float*)d_in[8];
  const float* cpb_w2  = (const float*)d_in[9];
  const float* rct     = (const float*)d_in[10];
  const float* gamma1  = (const float*)d_in[11];
  const float* beta1   = (const float*)d_in[12];
  const float* gamma2  = (const float*)d_in[13];
  const float* beta2   = (const float*)d_in[14];
  const float* fc1_w   = (const float*)d_in[15];
  const float* fc1_b   = (const float*)d_in[16];
  const float* fc2_w   = (const float*)d_in[17];
  const float* fc2_b   = (const float*)d_in[18];
  const int*   rpi     = (const int*)d_in[19];
  const float* amask   = (const float*)d_in[20];
  float* out = (float*)d_out;   // f32 output per reference dtype

  char* ws = (char*)d_ws;
  size_t cur = 0;
  auto alloc = [&](size_t bytes) { size_t o = cur; cur += (bytes + 255) & ~(size_t)255; return o; };
  size_t o_qkvb = alloc(1536 * 4);
  size_t o_pb   = alloc(512 * 4);
  size_t o_f1b  = alloc(2048 * 4);
  size_t o_f2b  = alloc(512 * 4);
  size_t o_scal = alloc(16 * 4);
  size_t o_tab  = alloc(169 * 16 * 4);
  size_t o_bias = alloc(16 * 2401 * 4);
  size_t o_bm   = alloc((size_t)64 * 16 * 2401 * 4);
  size_t o_wt1  = alloc((size_t)1536 * 512 * 2);
  size_t o_wt2  = alloc((size_t)512 * 512 * 2);
  size_t o_wt3  = alloc((size_t)2048 * 512 * 2);
  size_t o_wt4  = alloc((size_t)512 * 2048 * 2);
  size_t o_xb   = alloc((size_t)NROWS * 512 * 2);
  size_t o_x1b  = alloc((size_t)NROWS * 512 * 2);
  size_t o_big  = cur;
  size_t avail  = (ws_size > o_big) ? ws_size - o_big : 0;

  // --- adaptive tier selection from actual ws_size ---
  const int wopts[] = {1024, 512, 256, 128, 64, 32, 16, 8};
  int wA = 0, padA = 0;
  for (int i = 0; i < 8; ++i) {
    int rows = wopts[i] * 49;
    int pad = (rows + 127) & ~127;
    if ((size_t)pad * 1536 * 2 <= avail) { wA = wopts[i]; padA = pad; break; }
  }
  const int ropts[] = {25088, 12544, 6272, 3584, 1792, 896, 512, 256};
  int rB = 0;
  for (int i = 0; i < 8; ++i)
    if ((size_t)ropts[i] * 2560 * 2 <= avail) { rB = ropts[i]; break; }

  if (!wA || !rB) {
    float v = 20000.f + (float)(ws_size >> 20);
    diag_fill<<<(out_size + 255) / 256, 256, 0, stream>>>(out, v, out_size);
    return;
  }

  float* qkvb  = (float*)(ws + o_qkvb);
  float* pbf   = (float*)(ws + o_pb);
  float* f1bf  = (float*)(ws + o_f1b);
  float* f2bf  = (float*)(ws + o_f2b);
  float* scal  = (float*)(ws + o_scal);
  float* tab   = (float*)(ws + o_tab);
  float* biasF = (float*)(ws + o_bias);
  float* bmF   = (float*)(ws + o_bm);
  bf16* wt1 = (bf16*)(ws + o_wt1);
  bf16* wt2 = (bf16*)(ws + o_wt2);
  bf16* wt3 = (bf16*)(ws + o_wt3);
  bf16* wt4 = (bf16*)(ws + o_wt4);
  bf16* xb  = (bf16*)(ws + o_xb);
  bf16* x1b = (bf16*)(ws + o_x1b);
  bf16* big = (bf16*)(ws + o_big);

  transpose_f2b<<<dim3(48, 16), 256, 0, stream>>>(qkv_w, wt1, 512, 1536);
  transpose_f2b<<<dim3(16, 16), 256, 0, stream>>>(proj_w, wt2, 512, 512);
  transpose_f2b<<<dim3(64, 16), 256, 0, stream>>>(fc1_w, wt3, 512, 2048);
  transpose_f2b<<<dim3(16, 64), 256, 0, stream>>>(fc2_w, wt4, 2048, 512);
  conv_f2b<<<2048, 256, 0, stream>>>(x, xb, NROWS * 512 / 8);

  prep_small<<<8, 256, 0, stream>>>(q_bias, v_bias, proj_b, fc1_b, fc2_b, logit_s,
                                    qkvb, pbf, f1bf, f2bf, scal);
  prep_cpb<<<169, 256, 0, stream>>>(rct, cpb_w1, cpb_b1, cpb_w2, tab);
  prep_bias<<<151, 256, 0, stream>>>(tab, rpi, biasF);
  prep_bm<<<(64 * 16 * 2401 + 255) / 256, 256, 0, stream>>>(biasF, amask, bmF);

  // Phase A: qkv -> attn -> proj -> x1 = x + LN(proj) scattered into f32 out
  for (int woff = 0; woff < 1024; woff += wA) {
    int row_off = woff * 49;
    int rows = wA * 49;
    int nby = padA / 128;
    bf16* qkvC = big;   // [padA,1536]
    gemm_lds<1, 1><<<24 * nby, 256, 0, stream>>>(xb, 0, wt1, qkvC, 1536, qkvb, 512, 24, row_off);
    attn_mfma<<<wA * 4, 256, 0, stream>>>(qkvC, scal, bmF, qkvC, woff);
    gemm_lds<1, 0><<<8 * nby, 256, 0, stream>>>(qkvC, 1536, wt2, qkvC + 512, 1536, pbf, 512, 8, 0);
    ln_shift_add<<<rows, 256, 0, stream>>>(qkvC, x, gamma1, beta1, out, x1b, row_off);
  }
  // Phase B: fc1 -> fc2 -> out += LN(h2)  (in-place on f32 out rows)
  for (int r0 = 0; r0 < NROWS; r0 += rB) {
    float* x1h = out + (size_t)r0 * 512;
    bf16* hC  = big;                        // [rB,2048]
    bf16* f2C = big + (size_t)rB * 2048;    // [rB,512]
    int nby = rB / 128;
    gemm_lds<2, 0><<<32 * nby, 256, 0, stream>>>(x1b + (size_t)r0 * 512, 512, wt3, hC, 2048, f1bf, 512, 32, 0);
    gemm_lds<1, 0><<<8 * nby, 256, 0, stream>>>(hC, 2048, wt4, f2C, 512, f2bf, 2048, 8, 0);
    ln_add<<<rB, 256, 0, stream>>>(f2C, x1h, gamma2, beta2);
  }
}

// Round 9
// 890.085 us; speedup vs baseline: 1.1038x; 1.0765x over previous
//
#include <hip/hip_runtime.h>
#include <hip/hip_bf16.h>
#include <cmath>

typedef __hip_bfloat16 bf16;
typedef __attribute__((ext_vector_type(8))) __bf16 bf16x8;
typedef __attribute__((ext_vector_type(4))) float f32x4;
typedef __attribute__((ext_vector_type(4))) short short4v;

#define NROWS 50176   // 1024 windows * 49 tokens

static __device__ __forceinline__ float b2f(bf16 v) { return __bfloat162float(v); }
static __device__ __forceinline__ bf16 f2b(float v) { return __float2bfloat16(v); }

// async global->LDS 16B copy (dest must be linear: wave base + lane*16)
static __device__ __forceinline__ void gl16(const bf16* g, bf16* l) {
  __builtin_amdgcn_global_load_lds((const __attribute__((address_space(1))) void*)g,
                                   (__attribute__((address_space(3))) void*)l, 16, 0, 0);
}

// fast GELU: 0.5*v*(1+erf(v/sqrt2)), erf via A&S 7.1.26 (|eps|<=1.5e-7)
static __device__ __forceinline__ float fast_gelu(float v) {
  float z = v * 0.70710678118654752f;
  float a = fabsf(z);
  float t = __builtin_amdgcn_rcpf(fmaf(0.3275911f, a, 1.0f));
  float poly = t * fmaf(t, fmaf(t, fmaf(t, fmaf(t, 1.061405429f, -1.453152027f),
                                        1.421413741f), -0.284496736f), 0.254829592f);
  float e = exp2f(-a * a * 1.4426950408889634f);
  float erfz = copysignf(1.0f - poly * e, z);
  return 0.5f * v * (1.0f + erfz);
}

// map global window-row -> element base of pixel in x[16,56,56,512] after roll(-3,-3)
static __device__ __forceinline__ size_t pix_base(int row) {
  if (row >= NROWS) row = NROWS - 1;
  int win = row / 49, tok = row - win * 49;
  int b = win >> 6, wi = win & 63;
  int th = tok / 7, tw = tok - th * 7;
  int h = (wi >> 3) * 7 + th + 3; if (h >= 56) h -= 56;
  int w = (wi & 7) * 7 + tw + 3;  if (w >= 56) w -= 56;
  return (((size_t)b * 56 + h) * 56 + w) * 512;
}

// ---------------------------------------------------------------------------
__global__ __launch_bounds__(256) void diag_fill(float* out, float val, int n) {
  int i = blockIdx.x * 256 + threadIdx.x;
  if (i < n) out[i] = val;
}

// ---------------------------------------------------------------------------
// transpose f32 in[R][C] -> bf16 out[C][R]
__global__ __launch_bounds__(256) void transpose_f2b(const float* __restrict__ in,
                                                     bf16* __restrict__ out,
                                                     int R, int C) {
  __shared__ float tile[32][33];
  int c0 = blockIdx.x * 32, r0 = blockIdx.y * 32;
  int tx = threadIdx.x & 31, ty = threadIdx.x >> 5;
  for (int i = ty; i < 32; i += 8)
    tile[i][tx] = in[(size_t)(r0 + i) * C + c0 + tx];
  __syncthreads();
  for (int i = ty; i < 32; i += 8)
    out[(size_t)(c0 + i) * R + r0 + tx] = f2b(tile[tx][i]);
}

// f32 -> bf16 bulk convert (vectorized 8/thread)
__global__ __launch_bounds__(256) void conv_f2b(const float* __restrict__ in,
                                                bf16* __restrict__ outb, int n8) {
  for (int i = blockIdx.x * 256 + threadIdx.x; i < n8; i += gridDim.x * 256) {
    float4 u0 = *(const float4*)&in[(size_t)i * 8];
    float4 u1 = *(const float4*)&in[(size_t)i * 8 + 4];
    bf16 h8[8] = {f2b(u0.x), f2b(u0.y), f2b(u0.z), f2b(u0.w),
                  f2b(u1.x), f2b(u1.y), f2b(u1.z), f2b(u1.w)};
    *(uint4*)&outb[(size_t)i * 8] = *(uint4*)h8;
  }
}

// ---------------------------------------------------------------------------
__global__ void prep_small(const float* qb, const float* vb, const float* pb,
                           const float* f1b, const float* f2b_, const float* ls,
                           float* qkvb, float* pbf, float* f1bf, float* f2bf,
                           float* scale) {
  int tid = blockIdx.x * 256 + threadIdx.x;   // 0..2047
  if (tid < 512)       qkvb[tid] = qb[tid];
  else if (tid < 1024) qkvb[tid] = 0.f;
  else if (tid < 1536) qkvb[tid] = vb[tid - 1024];
  if (tid < 512)  pbf[tid]  = pb[tid];
  if (tid < 2048) f1bf[tid] = f1b[tid];
  if (tid < 512)  f2bf[tid] = f2b_[tid];
  if (tid < 16)   scale[tid] = expf(fminf(ls[tid], 4.6051701859880914f));
}

__global__ __launch_bounds__(256) void prep_cpb(const float* __restrict__ coords,
                                                const float* __restrict__ w1,
                                                const float* __restrict__ b1,
                                                const float* __restrict__ w2,
                                                float* __restrict__ table) {
  __shared__ float hid[512];
  __shared__ float part[256];
  int idx = blockIdx.x;   // 0..168
  float c0 = coords[idx * 2], c1 = coords[idx * 2 + 1];
  int tid = threadIdx.x;
  for (int h = tid; h < 512; h += 256) {
    float v = c0 * w1[h] + c1 * w1[512 + h] + b1[h];
    hid[h] = fmaxf(v, 0.f);
  }
  __syncthreads();
  int head = tid & 15, seg = tid >> 4;
  float s = 0.f;
  for (int h = seg * 32; h < seg * 32 + 32; ++h) s += hid[h] * w2[h * 16 + head];
  part[tid] = s;
  __syncthreads();
  if (tid < 16) {
    float t = 0.f;
    for (int sg = 0; sg < 16; ++sg) t += part[sg * 16 + tid];
    table[idx * 16 + tid] = t;
  }
}

__global__ void prep_bias(const float* __restrict__ table, const int* __restrict__ rpi,
                          float* __restrict__ bias_full) {
  int idx = blockIdx.x * 256 + threadIdx.x;
  if (idx >= 16 * 2401) return;
  int head = idx / 2401, ij = idx - head * 2401;
  float t = table[rpi[ij] * 16 + head];
  bias_full[idx] = 16.f / (1.f + expf(-t));
}

// combined bias+mask table: bm[w64][head][2401]
__global__ void prep_bm(const float* __restrict__ biasF, const float* __restrict__ amask,
                        float* __restrict__ bm) {
  int idx = blockIdx.x * 256 + threadIdx.x;
  if (idx >= 64 * 16 * 2401) return;
  int w = idx / (16 * 2401);
  int rem = idx - w * (16 * 2401);
  int h = rem / 2401, ij = rem - h * 2401;
  bm[idx] = biasF[h * 2401 + ij] + amask[w * 2401 + ij];
}

// ---------------------------------------------------------------------------
// bf16 MFMA GEMM, 128x128 tile, 4 waves of 64x64, 3-deep pipelined LDS:
// counted s_waitcnt vmcnt(8) + RAW s_barrier (no full drain in main loop),
// stage buffer kt+3 after the post-compute barrier.  48 KB LDS -> 3 blocks/CU.
// global_load_lds staging, linear LDS + XOR slot-swizzle on SOURCE address,
// inverse on fragment read (verified conflict-free).  Epilogue via padded LDS
// bounce -> 16B stores.  EPI: 1=bias, 2=bias+gelu.  GATHER: A via pix_base.
// 1D grid, bijective XCD swizzle.
template <int EPI, int GATHER>
__global__ __launch_bounds__(256, 3) void gemm_lds(const bf16* __restrict__ A, int lda,
                                                   const bf16* __restrict__ Bt,
                                                   bf16* __restrict__ C, int ldc,
                                                   const float* __restrict__ bias,
                                                   int K, int nbx, int row_off) {
  __shared__ __align__(16) char smem[49152];   // 3 buffers x (8KB A + 8KB B)
  bf16* Ct = (bf16*)smem;                      // epilogue overlay [128][136]

  const int nwg = gridDim.x, bid = blockIdx.x;
  const int q = nwg >> 3, r = nwg & 7;
  const int xcd = bid & 7, coff = bid >> 3;
  const int wg = (xcd < r ? xcd * (q + 1) : r * (q + 1) + (xcd - r) * q) + coff;
  const int bx = wg % nbx, by = wg / nbx;
  const int row0 = by * 128, col0 = bx * 128;

  const int tid = threadIdx.x;
  const int lane = tid & 63;
  const int quad = lane >> 4, l15 = lane & 15;
  const int wave = tid >> 6;
  const int wm = (wave >> 1) * 64, wn = (wave & 1) * 64;
  const int xq = quad ^ ((l15 >> 1) & 3);   // inverse of the staging swizzle

  // staging: A rows ar0=tid>>2, ar0+64; B rows (C-cols) same; slot as0=tid&3,
  // source slot XOR-swizzled so linear LDS reads back conflict-free via xq.
  const int ar0 = tid >> 2, as0 = tid & 3;
  const int ar1 = ar0 + 64;
  const int ax0 = as0 ^ ((ar0 >> 1) & 3);
  const int ax1 = as0 ^ ((ar1 >> 1) & 3);
  size_t ab0, ab1;
  if (GATHER) {
    ab0 = pix_base(row_off + row0 + ar0);
    ab1 = pix_base(row_off + row0 + ar1);
  } else {
    ab0 = (size_t)(row0 + ar0) * lda;
    ab1 = (size_t)(row0 + ar1) * lda;
  }
  const bf16* ap0 = A + ab0 + ax0 * 8;
  const bf16* ap1 = A + ab1 + ax1 * 8;
  const bf16* bp0 = Bt + (size_t)(col0 + ar0) * K + ax0 * 8;
  const bf16* bp1 = Bt + (size_t)(col0 + ar1) * K + ax1 * 8;

  f32x4 acc[4][4] = {};
  const int NK = K >> 5;   // K/32, >= 16 for all call sites

#define BUF_A(s) ((bf16*)(smem + (s) * 16384))
#define BUF_B(s) ((bf16*)(smem + (s) * 16384 + 8192))
#define STAGE(s, KK)                              \
  do {                                            \
    gl16(ap0 + (KK), BUF_A(s) + tid * 8);         \
    gl16(ap1 + (KK), BUF_A(s) + (tid + 256) * 8); \
    gl16(bp0 + (KK), BUF_B(s) + tid * 8);         \
    gl16(bp1 + (KK), BUF_B(s) + (tid + 256) * 8); \
  } while (0)

  STAGE(0, 0);
  STAGE(1, 32);
  STAGE(2, 64);

  int s = 0;
  for (int kt = 0; kt < NK; ++kt) {
    // wait ONLY the oldest buffer's 4 loads (8 newer stay in flight)
    if (kt + 2 < NK)      asm volatile("s_waitcnt vmcnt(8)" ::: "memory");
    else if (kt + 1 < NK) asm volatile("s_waitcnt vmcnt(4)" ::: "memory");
    else                  asm volatile("s_waitcnt vmcnt(0)" ::: "memory");
    __builtin_amdgcn_sched_barrier(0);
    __builtin_amdgcn_s_barrier();     // all waves' buf[s] loads retired
    __builtin_amdgcn_sched_barrier(0);
    {
      bf16x8 af[4], bfr[4];
#pragma unroll
      for (int t = 0; t < 4; ++t) {
        af[t]  = *(const bf16x8*)&BUF_A(s)[(wm + t * 16 + l15) * 32 + xq * 8];
        bfr[t] = *(const bf16x8*)&BUF_B(s)[(wn + t * 16 + l15) * 32 + xq * 8];
      }
#pragma unroll
      for (int mt = 0; mt < 4; ++mt)
#pragma unroll
        for (int nt = 0; nt < 4; ++nt)
          acc[mt][nt] = __builtin_amdgcn_mfma_f32_16x16x32_bf16(af[mt], bfr[nt], acc[mt][nt], 0, 0, 0);
    }
    __builtin_amdgcn_sched_barrier(0);
    __builtin_amdgcn_s_barrier();     // all waves done reading buf[s]
    __builtin_amdgcn_sched_barrier(0);
    if (kt + 3 < NK) STAGE(s, (kt + 3) * 32);
    s = (s == 2) ? 0 : s + 1;
  }
#undef STAGE
#undef BUF_A
#undef BUF_B

  // epilogue: acc -> padded LDS tile [128][136] -> vectorized 16B stores
#pragma unroll
  for (int nt = 0; nt < 4; ++nt) {
    int lcol = wn + nt * 16 + l15;
    float bv = bias[col0 + lcol];
#pragma unroll
    for (int mt = 0; mt < 4; ++mt) {
      int lrow = wm + mt * 16 + quad * 4;
#pragma unroll
      for (int rr = 0; rr < 4; ++rr) {
        float v = acc[mt][nt][rr] + bv;
        if (EPI == 2) v = fast_gelu(v);
        Ct[(lrow + rr) * 136 + lcol] = f2b(v);
      }
    }
  }
  __syncthreads();
#pragma unroll
  for (int i = 0; i < 8; ++i) {
    int chunk = tid + i * 256;           // 0..2047 = 128 rows x 16 chunks
    int rw = chunk >> 4, c16 = chunk & 15;
    uint4 val = *(const uint4*)&Ct[rw * 136 + c16 * 8];
    *(uint4*)&C[(size_t)(row0 + rw) * ldc + col0 + c16 * 8] = val;
  }
}

// ---------------------------------------------------------------------------
// Transposed-score MFMA cosine attention (unchanged from measured R4 winner).
__global__ __launch_bounds__(256, 4) void attn_mfma(const bf16* __restrict__ qkv,
                                                    const float* __restrict__ scale,
                                                    const float* __restrict__ bm,
                                                    bf16* __restrict__ outp, int win_off) {
  __shared__ __align__(16) __bf16 Vl[4][1984];   // per-wave V [49][40 pad]
  const int tid = threadIdx.x;
  const int wave = tid >> 6, lane = tid & 63;
  const int quad = lane >> 4, l15 = lane & 15;
  const int winl = blockIdx.x >> 2, hg = blockIdx.x & 3;
  const int head = hg * 4 + wave;
  const int wing = win_off + winl;
  const size_t rowbase = (size_t)winl * 49;
  const __bf16* base = (const __bf16*)qkv + rowbase * 1536 + head * 32;
  __bf16* Vw = Vl[wave];
  const float* bmh = bm + ((size_t)(wing & 63) * 16 + head) * 2401;
  const float sc = scale[head];

  bf16x8 vtmp[4];
  int vj[4], vdc[4];
#pragma unroll
  for (int t = 0; t < 4; ++t) {
    int c = lane + 64 * t; if (c > 195) c = 195;
    vj[t] = c >> 2; vdc[t] = (c & 3) << 3;
    vtmp[t] = *(const bf16x8*)(base + (size_t)vj[t] * 1536 + 1024 + vdc[t]);
  }

  bf16x8 khi[4], klo[4];
#pragma unroll
  for (int jt = 0; jt < 4; ++jt) {
    int j = jt * 16 + l15; if (j > 48) j = 48;
    bf16x8 raw = *(const bf16x8*)(base + (size_t)j * 1536 + 512 + quad * 8);
    float f[8]; float ss = 1e-20f;
#pragma unroll
    for (int e = 0; e < 8; ++e) { f[e] = (float)raw[e]; ss += f[e] * f[e]; }
    ss += __shfl_xor(ss, 16, 64);
    ss += __shfl_xor(ss, 32, 64);
    float inv = rsqrtf(ss);
#pragma unroll
    for (int e = 0; e < 8; ++e) {
      float v = f[e] * inv;
      __bf16 h = (__bf16)v;
      khi[jt][e] = h;
      klo[jt][e] = (__bf16)(v - (float)h);
    }
  }

#pragma unroll
  for (int t = 0; t < 4; ++t)
    *(bf16x8*)&Vw[vj[t] * 40 + vdc[t]] = vtmp[t];

  short4v vb[4][2];
#pragma unroll
  for (int jt = 0; jt < 4; ++jt)
#pragma unroll
    for (int n2 = 0; n2 < 2; ++n2) {
      short4v v;
#pragma unroll
      for (int e = 0; e < 4; ++e) {
        int j = jt * 16 + quad * 4 + e; if (j > 48) j = 48;
        v[e] = *(const short*)&Vw[j * 40 + n2 * 16 + l15];
      }
      vb[jt][n2] = v;
    }

  for (int it = 0; it < 4; ++it) {
    int qi = it * 16 + l15; if (qi > 48) qi = 48;
    bf16x8 raw = *(const bf16x8*)(base + (size_t)qi * 1536 + quad * 8);
    float f[8]; float ss = 1e-20f;
#pragma unroll
    for (int e = 0; e < 8; ++e) { f[e] = (float)raw[e]; ss += f[e] * f[e]; }
    ss += __shfl_xor(ss, 16, 64);
    ss += __shfl_xor(ss, 32, 64);
    float qinv = rsqrtf(ss) * sc;
    bf16x8 qhi, qlo;
#pragma unroll
    for (int e = 0; e < 8; ++e) {
      float v = f[e] * qinv;
      __bf16 h = (__bf16)v;
      qhi[e] = h;
      qlo[e] = (__bf16)(v - (float)h);
    }
    f32x4 s4[4];
#pragma unroll
    for (int jt = 0; jt < 4; ++jt) {
      f32x4 a = {0.f, 0.f, 0.f, 0.f};
      a = __builtin_amdgcn_mfma_f32_16x16x32_bf16(khi[jt], qhi, a, 0, 0, 0);
      a = __builtin_amdgcn_mfma_f32_16x16x32_bf16(klo[jt], qhi, a, 0, 0, 0);
      a = __builtin_amdgcn_mfma_f32_16x16x32_bf16(khi[jt], qlo, a, 0, 0, 0);
      s4[jt] = a;
    }
    int iio = qi * 49;
    float sv[4][4];
    float mx = -1e30f;
#pragma unroll
    for (int jt = 0; jt < 4; ++jt)
#pragma unroll
      for (int rr = 0; rr < 4; ++rr) {
        int j = jt * 16 + quad * 4 + rr;
        float s = (j < 49) ? s4[jt][rr] + bmh[iio + j] : -1e30f;
        sv[jt][rr] = s;
        mx = fmaxf(mx, s);
      }
    mx = fmaxf(mx, __shfl_xor(mx, 16, 64));
    mx = fmaxf(mx, __shfl_xor(mx, 32, 64));
    float sum = 0.f;
#pragma unroll
    for (int jt = 0; jt < 4; ++jt)
#pragma unroll
      for (int rr = 0; rr < 4; ++rr) {
        float e = exp2f((sv[jt][rr] - mx) * 1.4426950408889634f);
        sv[jt][rr] = e;
        sum += e;
      }
    sum += __shfl_xor(sum, 16, 64);
    sum += __shfl_xor(sum, 32, 64);
    float pinv = 1.f / sum;
    short4v pa[4];
#pragma unroll
    for (int jt = 0; jt < 4; ++jt)
#pragma unroll
      for (int rr = 0; rr < 4; ++rr) {
        __bf16 h = (__bf16)(sv[jt][rr] * pinv);
        pa[jt][rr] = *(short*)&h;
      }
    f32x4 o[2] = {};
#pragma unroll
    for (int jt = 0; jt < 4; ++jt) {
#pragma unroll
      for (int n2 = 0; n2 < 2; ++n2)
        o[n2] = __builtin_amdgcn_mfma_f32_16x16x16bf16_1k(pa[jt], vb[jt][n2], o[n2], 0, 0, 0);
    }
#pragma unroll
    for (int n2 = 0; n2 < 2; ++n2)
#pragma unroll
      for (int rr = 0; rr < 4; ++rr) {
        int i = it * 16 + quad * 4 + rr;
        if (i < 49)
          outp[(rowbase + i) * 1536 + head * 32 + n2 * 16 + l15] = f2b(o[n2][rr]);
      }
  }
}

// ---------------------------------------------------------------------------
// per (win,tok) row: x1 = x + LN(proj), scattered to pixel row of f32 out
// + bf16 copy x1b (feeds fc1 via global_load_lds)
__global__ __launch_bounds__(256) void ln_shift_add(const bf16* projq,
                                                    const float* __restrict__ x,
                                                    const float* __restrict__ gamma,
                                                    const float* __restrict__ beta,
                                                    float* __restrict__ x1,
                                                    bf16* __restrict__ x1b,
                                                    int row_off) {
  __shared__ float red[10];
  int grow = row_off + blockIdx.x;
  int win = grow / 49, tok = grow - win * 49;
  int b = win >> 6, wi = win & 63;
  int hs = (wi >> 3) * 7 + tok / 7;
  int wsc = (wi & 7) * 7 + tok % 7;
  int h = hs + 3; if (h >= 56) h -= 56;
  int w = wsc + 3; if (w >= 56) w -= 56;
  size_t pix = ((size_t)b * 56 + h) * 56 + w;
  const bf16* src = projq + (size_t)blockIdx.x * 1536 + 512;
  int tid = threadIdx.x;
  float a0 = b2f(src[tid]);
  float a1 = b2f(src[tid + 256]);
  float s = a0 + a1, qq = a0 * a0 + a1 * a1;
#pragma unroll
  for (int off = 32; off > 0; off >>= 1) {
    s += __shfl_down(s, off, 64);
    qq += __shfl_down(qq, off, 64);
  }
  int lane = tid & 63, wv = tid >> 6;
  if (lane == 0) { red[wv] = s; red[4 + wv] = qq; }
  __syncthreads();
  if (tid == 0) {
    red[8] = red[0] + red[1] + red[2] + red[3];
    red[9] = red[4] + red[5] + red[6] + red[7];
  }
  __syncthreads();
  float mu = red[8] * (1.f / 512.f);
  float inv = rsqrtf(fmaxf(red[9] * (1.f / 512.f) - mu * mu, 0.f) + 1e-5f);
  size_t base = pix * 512;
  float v0 = x[base + tid]       + (a0 - mu) * inv * gamma[tid]       + beta[tid];
  float v1 = x[base + tid + 256] + (a1 - mu) * inv * gamma[tid + 256] + beta[tid + 256];
  x1[base + tid]        = v0;
  x1[base + tid + 256]  = v1;
  x1b[base + tid]       = f2b(v0);
  x1b[base + tid + 256] = f2b(v1);
}

// out = x1 + LN(hsrc); x1/out alias (per-thread same-element RMW), f32
__global__ __launch_bounds__(256) void ln_add(const bf16* __restrict__ hsrc,
                                              float* x1,
                                              const float* __restrict__ gamma,
                                              const float* __restrict__ beta) {
  __shared__ float red[10];
  size_t base = (size_t)blockIdx.x * 512;
  int tid = threadIdx.x;
  float a0 = b2f(hsrc[base + tid]);
  float a1 = b2f(hsrc[base + tid + 256]);
  float s = a0 + a1, qq = a0 * a0 + a1 * a1;
#pragma unroll
  for (int off = 32; off > 0; off >>= 1) {
    s += __shfl_down(s, off, 64);
    qq += __shfl_down(qq, off, 64);
  }
  int lane = tid & 63, wv = tid >> 6;
  if (lane == 0) { red[wv] = s; red[4 + wv] = qq; }
  __syncthreads();
  if (tid == 0) {
    red[8] = red[0] + red[1] + red[2] + red[3];
    red[9] = red[4] + red[5] + red[6] + red[7];
  }
  __syncthreads();
  float mu = red[8] * (1.f / 512.f);
  float inv = rsqrtf(fmaxf(red[9] * (1.f / 512.f) - mu * mu, 0.f) + 1e-5f);
  x1[base + tid]       += (a0 - mu) * inv * gamma[tid]       + beta[tid];
  x1[base + tid + 256] += (a1 - mu) * inv * gamma[tid + 256] + beta[tid + 256];
}

// ---------------------------------------------------------------------------
extern "C" void kernel_launch(void* const* d_in, const int* in_sizes, int n_in,
                              void* d_out, int out_size, void* d_ws, size_t ws_size,
                              hipStream_t stream) {
  const float* x       = (const float*)d_in[0];
  const float* qkv_w   = (const float*)d_in[1];
  const float* q_bias  = (const float*)d_in[2];
  const float* v_bias  = (const float*)d_in[3];
  const float* proj_w  = (const float*)d_in[4];
  const float* proj_b  = (const float*)d_in[5];
  const float* logit_s = (const float*)d_in[6];
  const float* cpb_w1  = (const float*)d_in[7];
  const float* cpb_b1  = (const float*)d_in[8];
  const float* cpb_w2  = (const float*)d_in[9];
  const float* rct     = (const float*)d_in[10];
  const float* gamma1  = (const float*)d_in[11];
  const float* beta1   = (const float*)d_in[12];
  const float* gamma2  = (const float*)d_in[13];
  const float* beta2   = (const float*)d_in[14];
  const float* fc1_w   = (const float*)d_in[15];
  const float* fc1_b   = (const float*)d_in[16];
  const float* fc2_w   = (const float*)d_in[17];
  const float* fc2_b   = (const float*)d_in[18];
  const int*   rpi     = (const int*)d_in[19];
  const float* amask   = (const float*)d_in[20];
  float* out = (float*)d_out;   // f32 output per reference dtype

  char* ws = (char*)d_ws;
  size_t cur = 0;
  auto alloc = [&](size_t bytes) { size_t o = cur; cur += (bytes + 255) & ~(size_t)255; return o; };
  size_t o_qkvb = alloc(1536 * 4);
  size_t o_pb   = alloc(512 * 4);
  size_t o_f1b  = alloc(2048 * 4);
  size_t o_f2b  = alloc(512 * 4);
  size_t o_scal = alloc(16 * 4);
  size_t o_tab  = alloc(169 * 16 * 4);
  size_t o_bias = alloc(16 * 2401 * 4);
  size_t o_bm   = alloc((size_t)64 * 16 * 2401 * 4);
  size_t o_wt1  = alloc((size_t)1536 * 512 * 2);
  size_t o_wt2  = alloc((size_t)512 * 512 * 2);
  size_t o_wt3  = alloc((size_t)2048 * 512 * 2);
  size_t o_wt4  = alloc((size_t)512 * 2048 * 2);
  size_t o_xb   = alloc((size_t)NROWS * 512 * 2);
  size_t o_x1b  = alloc((size_t)NROWS * 512 * 2);
  size_t o_big  = cur;
  size_t avail  = (ws_size > o_big) ? ws_size - o_big : 0;

  // --- adaptive tier selection from actual ws_size ---
  const int wopts[] = {1024, 512, 256, 128, 64, 32, 16, 8};
  int wA = 0, padA = 0;
  for (int i = 0; i < 8; ++i) {
    int rows = wopts[i] * 49;
    int pad = (rows + 127) & ~127;
    if ((size_t)pad * 1536 * 2 <= avail) { wA = wopts[i]; padA = pad; break; }
  }
  const int ropts[] = {25088, 12544, 6272, 3584, 1792, 896, 512, 256};
  int rB = 0;
  for (int i = 0; i < 8; ++i)
    if ((size_t)ropts[i] * 2560 * 2 <= avail) { rB = ropts[i]; break; }

  if (!wA || !rB) {
    float v = 20000.f + (float)(ws_size >> 20);
    diag_fill<<<(out_size + 255) / 256, 256, 0, stream>>>(out, v, out_size);
    return;
  }

  float* qkvb  = (float*)(ws + o_qkvb);
  float* pbf   = (float*)(ws + o_pb);
  float* f1bf  = (float*)(ws + o_f1b);
  float* f2bf  = (float*)(ws + o_f2b);
  float* scal  = (float*)(ws + o_scal);
  float* tab   = (float*)(ws + o_tab);
  float* biasF = (float*)(ws + o_bias);
  float* bmF   = (float*)(ws + o_bm);
  bf16* wt1 = (bf16*)(ws + o_wt1);
  bf16* wt2 = (bf16*)(ws + o_wt2);
  bf16* wt3 = (bf16*)(ws + o_wt3);
  bf16* wt4 = (bf16*)(ws + o_wt4);
  bf16* xb  = (bf16*)(ws + o_xb);
  bf16* x1b = (bf16*)(ws + o_x1b);
  bf16* big = (bf16*)(ws + o_big);

  transpose_f2b<<<dim3(48, 16), 256, 0, stream>>>(qkv_w, wt1, 512, 1536);
  transpose_f2b<<<dim3(16, 16), 256, 0, stream>>>(proj_w, wt2, 512, 512);
  transpose_f2b<<<dim3(64, 16), 256, 0, stream>>>(fc1_w, wt3, 512, 2048);
  transpose_f2b<<<dim3(16, 64), 256, 0, stream>>>(fc2_w, wt4, 2048, 512);
  conv_f2b<<<2048, 256, 0, stream>>>(x, xb, NROWS * 512 / 8);

  prep_small<<<8, 256, 0, stream>>>(q_bias, v_bias, proj_b, fc1_b, fc2_b, logit_s,
                                    qkvb, pbf, f1bf, f2bf, scal);
  prep_cpb<<<169, 256, 0, stream>>>(rct, cpb_w1, cpb_b1, cpb_w2, tab);
  prep_bias<<<151, 256, 0, stream>>>(tab, rpi, biasF);
  prep_bm<<<(64 * 16 * 2401 + 255) / 256, 256, 0, stream>>>(biasF, amask, bmF);

  // Phase A: qkv -> attn -> proj -> x1 = x + LN(proj) scattered into f32 out
  for (int woff = 0; woff < 1024; woff += wA) {
    int row_off = woff * 49;
    int rows = wA * 49;
    int nby = padA / 128;
    bf16* qkvC = big;   // [padA,1536]
    gemm_lds<1, 1><<<12 * nby, 256, 0, stream>>>(xb, 0, wt1, qkvC, 1536, qkvb, 512, 12, row_off);
    attn_mfma<<<wA * 4, 256, 0, stream>>>(qkvC, scal, bmF, qkvC, woff);
    gemm_lds<1, 0><<<4 * nby, 256, 0, stream>>>(qkvC, 1536, wt2, qkvC + 512, 1536, pbf, 512, 4, 0);
    ln_shift_add<<<rows, 256, 0, stream>>>(qkvC, x, gamma1, beta1, out, x1b, row_off);
  }
  // Phase B: fc1 -> fc2 -> out += LN(h2)  (in-place on f32 out rows)
  for (int r0 = 0; r0 < NROWS; r0 += rB) {
    float* x1h = out + (size_t)r0 * 512;
    bf16* hC  = big;                        // [rB,2048]
    bf16* f2C = big + (size_t)rB * 2048;    // [rB,512]
    int nby = rB / 128;
    gemm_lds<2, 0><<<16 * nby, 256, 0, stream>>>(x1b + (size_t)r0 * 512, 512, wt3, hC, 2048, f1bf, 512, 16, 0);
    gemm_lds<1, 0><<<4 * nby, 256, 0, stream>>>(hC, 2048, wt4, f2C, 512, f2bf, 2048, 4, 0);
    ln_add<<<rB, 256, 0, stream>>>(f2C, x1h, gamma2, beta2);
  }
}